// Round 18
// baseline (60.007 us; speedup 1.0000x reference)
//
#include <hip/hip_runtime.h>

typedef __attribute__((ext_vector_type(8))) short bf16x8;
typedef __attribute__((ext_vector_type(4))) float f32x4;
typedef __attribute__((ext_vector_type(4))) unsigned int u32x4;

#define LOG2F 0.69314718055994531f
#define LOG2EF 1.4426950408889634f

// Problem dims (fixed by harness)
#define NB 16
#define NA 512
#define NN 64
#define NG 25
#define NF 128

__device__ __forceinline__ unsigned short f2bf(float x) {
    __bf16 h = (__bf16)x;                       // hw cvt (RNE), pairs to v_cvt_pk_bf16_f32
    return __builtin_bit_cast(unsigned short, h);
}
__device__ __forceinline__ float bf2f(unsigned short h) {
    union { unsigned int u; float f; } c; c.u = ((unsigned int)h) << 16;
    return c.f;
}
// ssp on pre-scaled input s = x*log2(e):  ln(1+e^x)-ln2 = ln2*(log2(1+2^s)-1)
__device__ __forceinline__ float ssp2(float s) {
    float t = __builtin_amdgcn_exp2f(s);                            // v_exp_f32
    return fmaf(__builtin_amdgcn_logf(1.0f + t), LOG2F, -LOG2F);    // add, v_log_f32, fma
}

// ws layout:
//   ushort frag[53248]:  [0,4096) Wf1^T A-frags (PRE-SCALED log2e) | [4096,20480) Wf2 B-frags
//                        [20480,36864) W_in2f B-frags | [36864,53248) W_out B-frags
//   byte 106496: float b1s[128] (b1 * log2e)
//   byte 107008: ushort ybf[8192*128]  (natural layout)
//   byte 2204160: float agg[8192*128]
#define FRAG_WF1 0
#define FRAG_WF2 4096
#define FRAG_WIN 20480
#define FRAG_WOUT 36864
#define B1S_OFF   106496
#define YBF_OFF   107008
#define AGG_OFF   2204160

__global__ __launch_bounds__(256) void k_prep(
    const float* __restrict__ Wf1, const float* __restrict__ Wf2,
    const float* __restrict__ Win, const float* __restrict__ Wout,
    const float* __restrict__ b1, char* __restrict__ ws)
{
    unsigned short* frag = (unsigned short*)ws;
    int idx = blockIdx.x * 256 + threadIdx.x;
    if (idx < 4096) {
        int j = idx & 7, lane = (idx >> 3) & 63, tc = idx >> 9;
        int f1 = tc * 16 + (lane & 15);
        int g  = (lane >> 4) * 8 + j;
        frag[idx] = (g < NG) ? f2bf(Wf1[g * NF + f1] * LOG2EF) : (unsigned short)0;
    } else if (idx < 20480) {
        int t = idx - 4096;
        int j = t & 7, lane = (t >> 3) & 63, ks = (t >> 9) & 3, tn = t >> 11;
        int f = tn * 16 + (lane & 15);
        int k = ks * 32 + (lane >> 4) * 8 + j;
        frag[idx] = f2bf(Wf2[k * NF + f]);
    } else if (idx < 36864) {
        int t = idx - 20480;
        int j = t & 7, lane = (t >> 3) & 63, ks = (t >> 9) & 3, tn = t >> 11;
        int f = tn * 16 + (lane & 15);
        int k = ks * 32 + (lane >> 4) * 8 + j;
        frag[idx] = f2bf(Win[k * NF + f]);
    } else if (idx < 53248) {
        int t = idx - 36864;
        int j = t & 7, lane = (t >> 3) & 63, ks = (t >> 9) & 3, tn = t >> 11;
        int f = tn * 16 + (lane & 15);
        int k = ks * 32 + (lane >> 4) * 8 + j;
        frag[idx] = f2bf(Wout[k * NF + f]);
    } else if (idx < 53376) {
        ((float*)(ws + B1S_OFF))[idx - 53248] = b1[idx - 53248] * LOG2EF;
    }
}

// y = x @ W_in2f  -> bf16, natural layout, rows = NB*NA = 8192, BM=32 (256 blocks)
__global__ __launch_bounds__(256) void k_in2f(
    const float* __restrict__ x, const unsigned short* __restrict__ frag,
    unsigned short* __restrict__ ybf)
{
    const unsigned short* winfrag = frag + FRAG_WIN;
    const int lane = threadIdx.x & 63, w = threadIdx.x >> 6;
    const int rowbase = blockIdx.x * 32;
    f32x4 acc[2][2];
    f32x4 z = {0.f, 0.f, 0.f, 0.f};
    acc[0][0] = z; acc[0][1] = z; acc[1][0] = z; acc[1][1] = z;
#pragma unroll
    for (int ks = 0; ks < 4; ++ks) {
        bf16x8 a[2];
#pragma unroll
        for (int tm = 0; tm < 2; ++tm) {
            int row = rowbase + tm * 16 + (lane & 15);
            int k0  = ks * 32 + (lane >> 4) * 8;
            const float* p = x + (size_t)row * NF + k0;
            float4 v0 = *(const float4*)p;
            float4 v1 = *(const float4*)(p + 4);
            bf16x8 t;
            t[0] = (short)f2bf(v0.x); t[1] = (short)f2bf(v0.y);
            t[2] = (short)f2bf(v0.z); t[3] = (short)f2bf(v0.w);
            t[4] = (short)f2bf(v1.x); t[5] = (short)f2bf(v1.y);
            t[6] = (short)f2bf(v1.z); t[7] = (short)f2bf(v1.w);
            a[tm] = t;
        }
#pragma unroll
        for (int tn = 0; tn < 2; ++tn) {
            bf16x8 bfr = *(const bf16x8*)(winfrag + ((((w * 2 + tn) * 4 + ks) * 64) + lane) * 8);
#pragma unroll
            for (int tm = 0; tm < 2; ++tm)
                acc[tm][tn] = __builtin_amdgcn_mfma_f32_16x16x32_bf16(a[tm], bfr, acc[tm][tn], 0, 0, 0);
        }
    }
#pragma unroll
    for (int tm = 0; tm < 2; ++tm)
#pragma unroll
        for (int tn = 0; tn < 2; ++tn)
#pragma unroll
            for (int r = 0; r < 4; ++r) {
                int row = rowbase + tm * 16 + (lane >> 4) * 4 + r;
                int f   = w * 32 + tn * 16 + (lane & 15);
                ybf[(size_t)row * NF + f] = f2bf(acc[tm][tn][r]);
            }
}

// Fused per-atom kernel: W1 = ssp(fij@Wf1+b1); W = W1@Wf2+b2; agg = sum_n W*mask*y[nbh]
// vs R13: (1) sfij and sW1T are SEPARATE (no overlay) -> the mid-barrier is gone
// (2 barriers total); (2) step C issues all 32 y-loads before consuming (32-deep MLP).
__global__ __launch_bounds__(256, 4) void k_cfconv(
    const float* __restrict__ fij, const int* __restrict__ nbh,
    const float* __restrict__ mask, const float* __restrict__ b1s,
    const float* __restrict__ b2, const unsigned short* __restrict__ frag,
    const unsigned short* __restrict__ ybf, float* __restrict__ agg)
{
    __shared__ alignas(16) float sfij[1600];           // raw [n][25] f32
    __shared__ alignas(16) unsigned short sW1T[8192];  // [n][k] bf16, XOR-swizzled
    __shared__ alignas(16) float smask[64];
    __shared__ alignas(16) int   snbh[64];

    const int tid = threadIdx.x, lane = tid & 63, w = tid >> 6;
    const int g = lane >> 4, lc = lane & 15;
    const int atom = blockIdx.x;
    const int bidx = atom >> 9;
    const int fbase = w * 32;
    const int fc0 = fbase + lc;

    if (tid < 64) {
        smask[tid] = mask[(size_t)atom * NN + tid];
        snbh[tid]  = nbh[(size_t)atom * NN + tid];
    }

    // ---- stage raw fij (6400B) -> LDS, 7 global_load_lds split across waves ----
    {
        const char* fb = (const char*)(fij + (size_t)atom * (NN * NG));
        __builtin_amdgcn_global_load_lds(
            (const __attribute__((address_space(1))) void*)(fb + w * 1024 + lane * 16),
            (__attribute__((address_space(3))) void*)((char*)sfij + w * 1024), 16, 0, 0);
        if (w < 2) {
            __builtin_amdgcn_global_load_lds(
                (const __attribute__((address_space(1))) void*)(fb + (w + 4) * 1024 + lane * 16),
                (__attribute__((address_space(3))) void*)((char*)sfij + (w + 4) * 1024), 16, 0, 0);
        }
        if (w == 3) {
            __builtin_amdgcn_global_load_lds(
                (const __attribute__((address_space(1))) void*)(fb + 6144 + lane * 4),
                (__attribute__((address_space(3))) void*)((char*)sfij + 6144), 4, 0, 0);
        }
    }

    // ---- A-frags (Wf1^T, pre-scaled by log2e) from global while staging lands ----
    const unsigned short* wf1frag = frag + FRAG_WF1;
    bf16x8 afr[2], vb[4];          // vb: fij B-frags now, sW1T A-frags later
    f32x4  rg[8];                  // rg: dW[2][4] now, acc[4][2] later
#pragma unroll
    for (int i = 0; i < 2; ++i)
        afr[i] = *(const bf16x8*)(wf1frag + (((2 * w + i) * 64) + lane) * 8);

    __syncthreads();   // barrier 1: sfij + smask/snbh visible (vmcnt drained)

    // ---- build fij B-frags from LDS -> vb: col n = tn*16+lc, k = g*8+j ----
    {
        const int g0 = g * 8;
        const unsigned int m0 = (g == 3) ? 0x0000FFFFu : 0xFFFFFFFFu;
        const unsigned int m1 = (g == 3) ? 0u : 0xFFFFFFFFu;
#pragma unroll
        for (int tn = 0; tn < 4; ++tn) {
            int n = tn * 16 + lc;
            const float* p = sfij + n * NG + g0;
            bf16x8 t;
            t[0] = (short)f2bf(p[0]); t[1] = (short)f2bf(p[1]);
            t[2] = (short)f2bf(p[2]); t[3] = (short)f2bf(p[3]);
            t[4] = (short)f2bf(p[4]); t[5] = (short)f2bf(p[5]);
            t[6] = (short)f2bf(p[6]); t[7] = (short)f2bf(p[7]);
            u32x4 tv = __builtin_bit_cast(u32x4, t);
            tv[0] &= m0; tv[1] &= m1; tv[2] &= m1; tv[3] &= m1;
            vb[tn] = __builtin_bit_cast(bf16x8, tv);
        }
    }

    // ---- step A: W1^T·log2e = (Wf1^T·log2e)(128x32) @ fij^T(32x64) + b1·log2e ----
    // rg[i*4+tn] = dW[i][tn]
#pragma unroll
    for (int i = 0; i < 2; ++i) {
        int c0 = (2 * w + i) * 16 + g * 4;
        f32x4 ci = *(const f32x4*)(b1s + c0);           // pre-scaled bias as MFMA C-in
#pragma unroll
        for (int tn = 0; tn < 4; ++tn)
            rg[i * 4 + tn] = __builtin_amdgcn_mfma_f32_16x16x32_bf16(afr[i], vb[tn], ci, 0, 0, 0);
    }

    // ssp (exp2 form) + pack -> swizzled LDS   (rg dies here)
#pragma unroll
    for (int i = 0; i < 2; ++i) {
        int c0 = (2 * w + i) * 16 + g * 4;
#pragma unroll
        for (int tn = 0; tn < 4; ++tn) {
            int n = tn * 16 + lc;
            ushort4 pk;
#pragma unroll
            for (int r = 0; r < 4; ++r)
                ((unsigned short*)&pk)[r] = f2bf(ssp2(rg[i * 4 + tn][r]));
            *(ushort4*)((char*)sW1T + n * 256 + ((c0 * 2) ^ ((n & 7) << 4))) = pk;
        }
    }
    __syncthreads();   // barrier 2: pack visible

    // ---- step B: W = W1(64x128) @ Wf2(128x128) + b2; wave f-slice [w*32, w*32+32) ----
    // rg[tm*2+tnl] = acc[tm][tnl]; vb[tm] reused as sW1T A-frags per ks
    const unsigned short* wf2frag = frag + FRAG_WF2;
    const float bias0 = b2[fc0], bias1 = b2[fc0 + 16];
#pragma unroll
    for (int tm = 0; tm < 4; ++tm) {
        rg[tm * 2 + 0] = f32x4{bias0, bias0, bias0, bias0};  // b2 folded into C-in
        rg[tm * 2 + 1] = f32x4{bias1, bias1, bias1, bias1};
    }
#pragma unroll
    for (int ks = 0; ks < 4; ++ks) {
#pragma unroll
        for (int tm = 0; tm < 4; ++tm) {
            int n  = tm * 16 + lc;
            int kb = ks * 64 + g * 16;             // byte offset of k0*2
            vb[tm] = *(const bf16x8*)((char*)sW1T + n * 256 + (kb ^ ((n & 7) << 4)));
        }
#pragma unroll
        for (int tnl = 0; tnl < 2; ++tnl) {
            int tn = w * 2 + tnl;
            bf16x8 bf2 = *(const bf16x8*)(wf2frag + (((tn * 4 + ks) * 64) + lane) * 8);
#pragma unroll
            for (int tm = 0; tm < 4; ++tm)
                rg[tm * 2 + tnl] = __builtin_amdgcn_mfma_f32_16x16x32_bf16(vb[tm], bf2, rg[tm * 2 + tnl], 0, 0, 0);
        }
    }

    // ---- step C: agg[f] = sum_n W[n][f] * mask[n] * y[b, nbh[n], f] ----
    // Phase 1: issue ALL 32 u16 loads (32-deep MLP on L2 latency).
    // Phase 2: consume with fmaf. Live range is step-C-local (+32 regs, stays in
    // the 65-128 / 4-waves-per-SIMD band — unlike R12's across-A+B version).
    float aggv0 = 0.f, aggv1 = 0.f;
    const unsigned short* yb = ybf + (size_t)bidx * NA * NF;
    unsigned short y0v[16], y1v[16];
#pragma unroll
    for (int tm = 0; tm < 4; ++tm) {
        int4 nb4 = *(const int4*)(snbh + tm * 16 + g * 4);
#pragma unroll
        for (int r = 0; r < 4; ++r) {
            int yrow = (r == 0) ? nb4.x : (r == 1) ? nb4.y : (r == 2) ? nb4.z : nb4.w;
            const unsigned short* yp = yb + (size_t)yrow * NF + fc0;
            y0v[tm * 4 + r] = yp[0];
            y1v[tm * 4 + r] = yp[16];
        }
    }
#pragma unroll
    for (int tm = 0; tm < 4; ++tm) {
        f32x4 m4 = *(const f32x4*)(smask + tm * 16 + g * 4);
#pragma unroll
        for (int r = 0; r < 4; ++r) {
            float y0 = bf2f(y0v[tm * 4 + r]);
            float y1 = bf2f(y1v[tm * 4 + r]);
            aggv0 = fmaf(rg[tm * 2 + 0][r] * m4[r], y0, aggv0);
            aggv1 = fmaf(rg[tm * 2 + 1][r] * m4[r], y1, aggv1);
        }
    }
    aggv0 += __shfl_xor(aggv0, 16); aggv1 += __shfl_xor(aggv1, 16);
    aggv0 += __shfl_xor(aggv0, 32); aggv1 += __shfl_xor(aggv1, 32);
    if (lane < 16) {
        float* ap = agg + (size_t)atom * NF + fbase;
        ap[lane] = aggv0;
        ap[16 + lane] = aggv1;
    }
}

// out = ssp(agg @ W_out + b_out), rows = 8192, BM=32 (256 blocks)
__global__ __launch_bounds__(256) void k_out(
    const float* __restrict__ agg, const unsigned short* __restrict__ frag,
    const float* __restrict__ bout, float* __restrict__ out)
{
    const unsigned short* wofrag = frag + FRAG_WOUT;
    const int lane = threadIdx.x & 63, w = threadIdx.x >> 6;
    const int rowbase = blockIdx.x * 32;
    const int f0 = w * 32 + (lane & 15);
    const float bo0 = bout[f0], bo1 = bout[f0 + 16];
    f32x4 acc[2][2];
    acc[0][0] = f32x4{bo0, bo0, bo0, bo0};
    acc[1][0] = f32x4{bo0, bo0, bo0, bo0};
    acc[0][1] = f32x4{bo1, bo1, bo1, bo1};
    acc[1][1] = f32x4{bo1, bo1, bo1, bo1};
#pragma unroll
    for (int ks = 0; ks < 4; ++ks) {
        bf16x8 a[2];
#pragma unroll
        for (int tm = 0; tm < 2; ++tm) {
            int row = rowbase + tm * 16 + (lane & 15);
            int k0  = ks * 32 + (lane >> 4) * 8;
            const float* p = agg + (size_t)row * NF + k0;
            float4 v0 = *(const float4*)p;
            float4 v1 = *(const float4*)(p + 4);
            bf16x8 t;
            t[0] = (short)f2bf(v0.x); t[1] = (short)f2bf(v0.y);
            t[2] = (short)f2bf(v0.z); t[3] = (short)f2bf(v0.w);
            t[4] = (short)f2bf(v1.x); t[5] = (short)f2bf(v1.y);
            t[6] = (short)f2bf(v1.z); t[7] = (short)f2bf(v1.w);
            a[tm] = t;
        }
#pragma unroll
        for (int tn = 0; tn < 2; ++tn) {
            bf16x8 bfr = *(const bf16x8*)(wofrag + ((((w * 2 + tn) * 4 + ks) * 64) + lane) * 8);
#pragma unroll
            for (int tm = 0; tm < 2; ++tm)
                acc[tm][tn] = __builtin_amdgcn_mfma_f32_16x16x32_bf16(a[tm], bfr, acc[tm][tn], 0, 0, 0);
        }
    }
    float lg2 = LOG2EF;
#pragma unroll
    for (int tm = 0; tm < 2; ++tm)
#pragma unroll
        for (int tn = 0; tn < 2; ++tn)
#pragma unroll
            for (int r = 0; r < 4; ++r) {
                int row = rowbase + tm * 16 + (lane >> 4) * 4 + r;
                int f   = w * 32 + tn * 16 + (lane & 15);
                out[(size_t)row * NF + f] = ssp2(acc[tm][tn][r] * lg2);
            }
}

extern "C" void kernel_launch(void* const* d_in, const int* in_sizes, int n_in,
                              void* d_out, int out_size, void* d_ws, size_t ws_size,
                              hipStream_t stream)
{
    (void)in_sizes; (void)n_in; (void)out_size; (void)ws_size;
    const float* x    = (const float*)d_in[0];
    // d_in[1] = r_ij (unused by reference)
    const float* fij  = (const float*)d_in[2];
    const int*   nbh  = (const int*)d_in[3];
    const float* mask = (const float*)d_in[4];
    const float* Win  = (const float*)d_in[5];
    const float* Wf1  = (const float*)d_in[6];
    const float* b1   = (const float*)d_in[7];
    const float* Wf2  = (const float*)d_in[8];
    const float* b2   = (const float*)d_in[9];
    const float* Wout = (const float*)d_in[10];
    const float* bout = (const float*)d_in[11];
    float* out = (float*)d_out;

    char* ws = (char*)d_ws;
    unsigned short* frag = (unsigned short*)ws;
    const float*    b1s  = (const float*)(ws + B1S_OFF);
    unsigned short* ybf  = (unsigned short*)(ws + YBF_OFF);
    float*          agg  = (float*)(ws + AGG_OFF);

    k_prep  <<<209,  256, 0, stream>>>(Wf1, Wf2, Win, Wout, b1, ws);
    k_in2f  <<<256,  256, 0, stream>>>(x, frag, ybf);
    k_cfconv<<<8192, 256, 0, stream>>>(fij, nbh, mask, b1s, b2, frag, ybf, agg);
    k_out   <<<256,  256, 0, stream>>>(agg, frag, bout, out);
}

// Round 20
// 57.757 us; speedup vs baseline: 1.0390x; 1.0390x over previous
//
#include <hip/hip_runtime.h>

typedef __attribute__((ext_vector_type(8))) short bf16x8;
typedef __attribute__((ext_vector_type(4))) float f32x4;
typedef __attribute__((ext_vector_type(4))) unsigned int u32x4;

#define LOG2F 0.69314718055994531f
#define LOG2EF 1.4426950408889634f

// Problem dims (fixed by harness)
#define NB 16
#define NA 512
#define NN 64
#define NG 25
#define NF 128

__device__ __forceinline__ unsigned short f2bf(float x) {
    __bf16 h = (__bf16)x;                       // hw cvt (RNE), pairs to v_cvt_pk_bf16_f32
    return __builtin_bit_cast(unsigned short, h);
}
__device__ __forceinline__ float bf2f(unsigned short h) {
    union { unsigned int u; float f; } c; c.u = ((unsigned int)h) << 16;
    return c.f;
}
// ssp on pre-scaled input s = x*log2(e):  ln(1+e^x)-ln2 = ln2*(log2(1+2^s)-1)
// (stored in bf16: values ~0.3 -> fine grid. L-form (~1.0) failed accuracy in R19.)
__device__ __forceinline__ float ssp2(float s) {
    float t = __builtin_amdgcn_exp2f(s);                            // v_exp_f32
    return fmaf(__builtin_amdgcn_logf(1.0f + t), LOG2F, -LOG2F);    // add, v_log_f32, fma
}

// ws layout:
//   ushort frag[53248]:  [0,4096) Wf1^T A-frags (PRE-SCALED log2e) | [4096,20480) Wf2 B-frags
//                        [20480,36864) W_in2f B-frags | [36864,53248) W_out B-frags
//   byte 106496: float b1s[128]  (b1 * log2e)
//   byte 107008: ushort ybf[8192*128]   (natural layout)
//   byte 2204160: ushort aggbf[8192*128] (agg in bf16 — bit-identical to f32 store + k_out cvt)
#define FRAG_WF1 0
#define FRAG_WF2 4096
#define FRAG_WIN 20480
#define FRAG_WOUT 36864
#define B1S_OFF   106496
#define YBF_OFF   107008
#define AGG_OFF   2204160

__global__ __launch_bounds__(256) void k_prep(
    const float* __restrict__ Wf1, const float* __restrict__ Wf2,
    const float* __restrict__ Win, const float* __restrict__ Wout,
    const float* __restrict__ b1, char* __restrict__ ws)
{
    unsigned short* frag = (unsigned short*)ws;
    int idx = blockIdx.x * 256 + threadIdx.x;
    if (idx < 4096) {
        int j = idx & 7, lane = (idx >> 3) & 63, tc = idx >> 9;
        int f1 = tc * 16 + (lane & 15);
        int g  = (lane >> 4) * 8 + j;
        frag[idx] = (g < NG) ? f2bf(Wf1[g * NF + f1] * LOG2EF) : (unsigned short)0;
    } else if (idx < 20480) {
        int t = idx - 4096;
        int j = t & 7, lane = (t >> 3) & 63, ks = (t >> 9) & 3, tn = t >> 11;
        int f = tn * 16 + (lane & 15);
        int k = ks * 32 + (lane >> 4) * 8 + j;
        frag[idx] = f2bf(Wf2[k * NF + f]);
    } else if (idx < 36864) {
        int t = idx - 20480;
        int j = t & 7, lane = (t >> 3) & 63, ks = (t >> 9) & 3, tn = t >> 11;
        int f = tn * 16 + (lane & 15);
        int k = ks * 32 + (lane >> 4) * 8 + j;
        frag[idx] = f2bf(Win[k * NF + f]);
    } else if (idx < 53248) {
        int t = idx - 36864;
        int j = t & 7, lane = (t >> 3) & 63, ks = (t >> 9) & 3, tn = t >> 11;
        int f = tn * 16 + (lane & 15);
        int k = ks * 32 + (lane >> 4) * 8 + j;
        frag[idx] = f2bf(Wout[k * NF + f]);
    } else if (idx < 53376) {
        ((float*)(ws + B1S_OFF))[idx - 53248] = b1[idx - 53248] * LOG2EF;
    }
}

// y = x @ W_in2f  -> bf16, natural layout, rows = NB*NA = 8192, BM=32 (256 blocks)
__global__ __launch_bounds__(256) void k_in2f(
    const float* __restrict__ x, const unsigned short* __restrict__ frag,
    unsigned short* __restrict__ ybf)
{
    const unsigned short* winfrag = frag + FRAG_WIN;
    const int lane = threadIdx.x & 63, w = threadIdx.x >> 6;
    const int rowbase = blockIdx.x * 32;
    f32x4 acc[2][2];
    f32x4 z = {0.f, 0.f, 0.f, 0.f};
    acc[0][0] = z; acc[0][1] = z; acc[1][0] = z; acc[1][1] = z;
#pragma unroll
    for (int ks = 0; ks < 4; ++ks) {
        bf16x8 a[2];
#pragma unroll
        for (int tm = 0; tm < 2; ++tm) {
            int row = rowbase + tm * 16 + (lane & 15);
            int k0  = ks * 32 + (lane >> 4) * 8;
            const float* p = x + (size_t)row * NF + k0;
            float4 v0 = *(const float4*)p;
            float4 v1 = *(const float4*)(p + 4);
            bf16x8 t;
            t[0] = (short)f2bf(v0.x); t[1] = (short)f2bf(v0.y);
            t[2] = (short)f2bf(v0.z); t[3] = (short)f2bf(v0.w);
            t[4] = (short)f2bf(v1.x); t[5] = (short)f2bf(v1.y);
            t[6] = (short)f2bf(v1.z); t[7] = (short)f2bf(v1.w);
            a[tm] = t;
        }
#pragma unroll
        for (int tn = 0; tn < 2; ++tn) {
            bf16x8 bfr = *(const bf16x8*)(winfrag + ((((w * 2 + tn) * 4 + ks) * 64) + lane) * 8);
#pragma unroll
            for (int tm = 0; tm < 2; ++tm)
                acc[tm][tn] = __builtin_amdgcn_mfma_f32_16x16x32_bf16(a[tm], bfr, acc[tm][tn], 0, 0, 0);
        }
    }
#pragma unroll
    for (int tm = 0; tm < 2; ++tm)
#pragma unroll
        for (int tn = 0; tn < 2; ++tn)
#pragma unroll
            for (int r = 0; r < 4; ++r) {
                int row = rowbase + tm * 16 + (lane >> 4) * 4 + r;
                int f   = w * 32 + tn * 16 + (lane & 15);
                ybf[(size_t)row * NF + f] = f2bf(acc[tm][tn][r]);
            }
}

// Fused per-atom kernel (R13/R17 structure + exact micro-cuts only):
// W1 = ssp(fij@Wf1+b1); W = W1@Wf2+b2; agg = sum_n W*mask*y[nbh] -> bf16
// Cuts: snbh as byte offsets; single-vaddr vb build; agg stored bf16.
__global__ __launch_bounds__(256, 4) void k_cfconv(
    const float* __restrict__ fij, const int* __restrict__ nbh,
    const float* __restrict__ mask, const float* __restrict__ b1s,
    const float* __restrict__ b2, const unsigned short* __restrict__ frag,
    const unsigned short* __restrict__ ybf, unsigned short* __restrict__ aggbf)
{
    __shared__ alignas(16) char smem[16896];
    float* sfij          = (float*)smem;            // [0, 6400)  raw [n][25] f32 (phase 1)
    unsigned short* sW1T = (unsigned short*)smem;   // [0,16384)  [n][k] bf16 swizzled (phase 2)
    float* smask         = (float*)(smem + 16384);
    int*   snoff         = (int*)(smem + 16640);    // y-row BYTE offsets (nbh*256)

    const int tid = threadIdx.x, lane = tid & 63, w = tid >> 6;
    const int g = lane >> 4, lc = lane & 15;
    const int atom = blockIdx.x;
    const int bidx = atom >> 9;
    const int fbase = w * 32;
    const int fc0 = fbase + lc;

    if (tid < 64) {
        smask[tid] = mask[(size_t)atom * NN + tid];
        snoff[tid] = nbh[(size_t)atom * NN + tid] << 8;   // *NF*2 bytes
    }

    // ---- stage raw fij (6400B) -> LDS, 7 global_load_lds split across waves ----
    {
        const char* fb = (const char*)(fij + (size_t)atom * (NN * NG));
        __builtin_amdgcn_global_load_lds(
            (const __attribute__((address_space(1))) void*)(fb + w * 1024 + lane * 16),
            (__attribute__((address_space(3))) void*)((char*)sfij + w * 1024), 16, 0, 0);
        if (w < 2) {
            __builtin_amdgcn_global_load_lds(
                (const __attribute__((address_space(1))) void*)(fb + (w + 4) * 1024 + lane * 16),
                (__attribute__((address_space(3))) void*)((char*)sfij + (w + 4) * 1024), 16, 0, 0);
        }
        if (w == 3) {
            __builtin_amdgcn_global_load_lds(
                (const __attribute__((address_space(1))) void*)(fb + 6144 + lane * 4),
                (__attribute__((address_space(3))) void*)((char*)sfij + 6144), 4, 0, 0);
        }
    }

    // ---- A-frags (Wf1^T, pre-scaled by log2e) from global while staging lands ----
    const unsigned short* wf1frag = frag + FRAG_WF1;
    bf16x8 afr[2], vb[4];          // vb: fij B-frags now, sW1T A-frags later
    f32x4  rg[8];                  // rg: dW[2][4] now, acc[4][2] later
#pragma unroll
    for (int i = 0; i < 2; ++i)
        afr[i] = *(const bf16x8*)(wf1frag + (((2 * w + i) * 64) + lane) * 8);

    __syncthreads();   // sfij + smask/snoff visible (vmcnt drained before s_barrier)

    // ---- build fij B-frags from LDS -> vb: ONE vaddr, all offsets compile-time ----
    {
        const float* base = sfij + lc * NG + g * 8;   // n=tn*16+lc -> +tn*400 floats (imm)
        const unsigned int m0 = (g == 3) ? 0x0000FFFFu : 0xFFFFFFFFu;
        const unsigned int m1 = (g == 3) ? 0u : 0xFFFFFFFFu;
#pragma unroll
        for (int tn = 0; tn < 4; ++tn) {
            const float* p = base + tn * 400;
            bf16x8 t;
            t[0] = (short)f2bf(p[0]); t[1] = (short)f2bf(p[1]);
            t[2] = (short)f2bf(p[2]); t[3] = (short)f2bf(p[3]);
            t[4] = (short)f2bf(p[4]); t[5] = (short)f2bf(p[5]);
            t[6] = (short)f2bf(p[6]); t[7] = (short)f2bf(p[7]);
            u32x4 tv = __builtin_bit_cast(u32x4, t);
            tv[0] &= m0; tv[1] &= m1; tv[2] &= m1; tv[3] &= m1;
            vb[tn] = __builtin_bit_cast(bf16x8, tv);
        }
    }

    __syncthreads();   // all sfij reads done -> safe to overwrite smem with sW1T

    // ---- step A: W1^T·log2e = (Wf1^T·log2e)(128x32) @ fij^T(32x64) + b1·log2e ----
#pragma unroll
    for (int i = 0; i < 2; ++i) {
        int c0 = (2 * w + i) * 16 + g * 4;
        f32x4 ci = *(const f32x4*)(b1s + c0);           // pre-scaled bias as MFMA C-in
#pragma unroll
        for (int tn = 0; tn < 4; ++tn)
            rg[i * 4 + tn] = __builtin_amdgcn_mfma_f32_16x16x32_bf16(afr[i], vb[tn], ci, 0, 0, 0);
    }

    // ssp (exp2 form) + pack -> swizzled LDS   (rg dies here)
#pragma unroll
    for (int i = 0; i < 2; ++i) {
        int c0 = (2 * w + i) * 16 + g * 4;
#pragma unroll
        for (int tn = 0; tn < 4; ++tn) {
            int n = tn * 16 + lc;
            ushort4 pk;
#pragma unroll
            for (int r = 0; r < 4; ++r)
                ((unsigned short*)&pk)[r] = f2bf(ssp2(rg[i * 4 + tn][r]));
            *(ushort4*)((char*)sW1T + n * 256 + ((c0 * 2) ^ ((n & 7) << 4))) = pk;
        }
    }
    __syncthreads();

    // ---- step B: W = W1(64x128) @ Wf2(128x128) + b2; wave f-slice [w*32, w*32+32) ----
    const unsigned short* wf2frag = frag + FRAG_WF2;
    const float bias0 = b2[fc0], bias1 = b2[fc0 + 16];
#pragma unroll
    for (int tm = 0; tm < 4; ++tm) {
        rg[tm * 2 + 0] = f32x4{bias0, bias0, bias0, bias0};  // b2 folded into C-in
        rg[tm * 2 + 1] = f32x4{bias1, bias1, bias1, bias1};
    }
#pragma unroll
    for (int ks = 0; ks < 4; ++ks) {
#pragma unroll
        for (int tm = 0; tm < 4; ++tm) {
            int n  = tm * 16 + lc;
            int kb = ks * 64 + g * 16;             // byte offset of k0*2
            vb[tm] = *(const bf16x8*)((char*)sW1T + n * 256 + (kb ^ ((n & 7) << 4)));
        }
#pragma unroll
        for (int tnl = 0; tnl < 2; ++tnl) {
            int tn = w * 2 + tnl;
            bf16x8 bf2 = *(const bf16x8*)(wf2frag + (((tn * 4 + ks) * 64) + lane) * 8);
#pragma unroll
            for (int tm = 0; tm < 4; ++tm)
                rg[tm * 2 + tnl] = __builtin_amdgcn_mfma_f32_16x16x32_bf16(vb[tm], bf2, rg[tm * 2 + tnl], 0, 0, 0);
        }
    }

    // ---- step C: agg[f] = sum_n W[n][f] * mask[n] * y[b, nbh[n], f] ----
    // snoff holds byte offsets; per-row addr = ybyte + off (1 add, no shifts).
    float aggv0 = 0.f, aggv1 = 0.f;
    const char* ybyte = (const char*)(ybf + (size_t)bidx * NA * NF) + fc0 * 2;
#pragma unroll
    for (int tm = 0; tm < 4; ++tm) {
        f32x4 m4 = *(const f32x4*)(smask + tm * 16 + g * 4);
        int4  of4 = *(const int4*)(snoff + tm * 16 + g * 4);
#pragma unroll
        for (int r = 0; r < 4; ++r) {
            int off = (r == 0) ? of4.x : (r == 1) ? of4.y : (r == 2) ? of4.z : of4.w;
            const unsigned short* yp = (const unsigned short*)(ybyte + off);
            float y0 = __builtin_bit_cast(float, (unsigned int)yp[0] << 16);
            float y1 = __builtin_bit_cast(float, (unsigned int)yp[16] << 16);
            aggv0 = fmaf(rg[tm * 2 + 0][r] * m4[r], y0, aggv0);
            aggv1 = fmaf(rg[tm * 2 + 1][r] * m4[r], y1, aggv1);
        }
    }
    aggv0 += __shfl_xor(aggv0, 16); aggv1 += __shfl_xor(aggv1, 16);
    aggv0 += __shfl_xor(aggv0, 32); aggv1 += __shfl_xor(aggv1, 32);
    if (lane < 16) {
        unsigned short* ap = aggbf + (size_t)atom * NF + fbase;
        ap[lane] = f2bf(aggv0);          // bf16 store == old f32 store + k_out cvt (same RNE)
        ap[16 + lane] = f2bf(aggv1);
    }
}

// out = ssp(agg @ W_out + b_out), rows = 8192, BM=32 (256 blocks); agg already bf16
__global__ __launch_bounds__(256) void k_out(
    const unsigned short* __restrict__ aggbf, const unsigned short* __restrict__ frag,
    const float* __restrict__ bout, float* __restrict__ out)
{
    const unsigned short* wofrag = frag + FRAG_WOUT;
    const int lane = threadIdx.x & 63, w = threadIdx.x >> 6;
    const int rowbase = blockIdx.x * 32;
    const int f0 = w * 32 + (lane & 15);
    const float bo0 = bout[f0], bo1 = bout[f0 + 16];
    f32x4 acc[2][2];
    acc[0][0] = f32x4{bo0, bo0, bo0, bo0};
    acc[1][0] = f32x4{bo0, bo0, bo0, bo0};
    acc[0][1] = f32x4{bo1, bo1, bo1, bo1};
    acc[1][1] = f32x4{bo1, bo1, bo1, bo1};
#pragma unroll
    for (int ks = 0; ks < 4; ++ks) {
        bf16x8 a[2];
#pragma unroll
        for (int tm = 0; tm < 2; ++tm) {
            int row = rowbase + tm * 16 + (lane & 15);
            int k0  = ks * 32 + (lane >> 4) * 8;
            a[tm] = *(const bf16x8*)(aggbf + (size_t)row * NF + k0);  // direct bf16 frag load
        }
#pragma unroll
        for (int tn = 0; tn < 2; ++tn) {
            bf16x8 bfr = *(const bf16x8*)(wofrag + ((((w * 2 + tn) * 4 + ks) * 64) + lane) * 8);
#pragma unroll
            for (int tm = 0; tm < 2; ++tm)
                acc[tm][tn] = __builtin_amdgcn_mfma_f32_16x16x32_bf16(a[tm], bfr, acc[tm][tn], 0, 0, 0);
        }
    }
    float lg2 = LOG2EF;
#pragma unroll
    for (int tm = 0; tm < 2; ++tm)
#pragma unroll
        for (int tn = 0; tn < 2; ++tn)
#pragma unroll
            for (int r = 0; r < 4; ++r) {
                int row = rowbase + tm * 16 + (lane >> 4) * 4 + r;
                int f   = w * 32 + tn * 16 + (lane & 15);
                out[(size_t)row * NF + f] = ssp2(acc[tm][tn][r] * lg2);
            }
}

extern "C" void kernel_launch(void* const* d_in, const int* in_sizes, int n_in,
                              void* d_out, int out_size, void* d_ws, size_t ws_size,
                              hipStream_t stream)
{
    (void)in_sizes; (void)n_in; (void)out_size; (void)ws_size;
    const float* x    = (const float*)d_in[0];
    // d_in[1] = r_ij (unused by reference)
    const float* fij  = (const float*)d_in[2];
    const int*   nbh  = (const int*)d_in[3];
    const float* mask = (const float*)d_in[4];
    const float* Win  = (const float*)d_in[5];
    const float* Wf1  = (const float*)d_in[6];
    const float* b1   = (const float*)d_in[7];
    const float* Wf2  = (const float*)d_in[8];
    const float* b2   = (const float*)d_in[9];
    const float* Wout = (const float*)d_in[10];
    const float* bout = (const float*)d_in[11];
    float* out = (float*)d_out;

    char* ws = (char*)d_ws;
    unsigned short* frag = (unsigned short*)ws;
    const float*    b1s  = (const float*)(ws + B1S_OFF);
    unsigned short* ybf  = (unsigned short*)(ws + YBF_OFF);
    unsigned short* aggbf = (unsigned short*)(ws + AGG_OFF);

    k_prep  <<<209,  256, 0, stream>>>(Wf1, Wf2, Win, Wout, b1, ws);
    k_in2f  <<<256,  256, 0, stream>>>(x, frag, ybf);
    k_cfconv<<<8192, 256, 0, stream>>>(fij, nbh, mask, b1s, b2, frag, ybf, aggbf);
    k_out   <<<256,  256, 0, stream>>>(aggbf, frag, bout, out);
}